// Round 1
// baseline (356.606 us; speedup 1.0000x reference)
//
#include <hip/hip_runtime.h>
#include <stdint.h>

#define N_NODES 6144
#define NHEAD 4
#define HDIM 32
#define CDIM 128

typedef float f32x4 __attribute__((ext_vector_type(4)));
typedef short short8 __attribute__((ext_vector_type(8)));

__device__ __forceinline__ unsigned short f2bf(float f) {
  union { float f; unsigned int u; } v; v.f = f;
  unsigned int u = v.u;
  u += 0x7FFFu + ((u >> 16) & 1u);
  return (unsigned short)(u >> 16);
}

// K1: h = x*W (fp32), write hfT (bf16, [c][n] transposed), s_src/s_dst via atomics.
__global__ __launch_bounds__(256) void k1_feat(const float* __restrict__ x,
                                               const float* __restrict__ W,
                                               const float* __restrict__ a,
                                               unsigned short* __restrict__ hfT,
                                               float* __restrict__ s_src,
                                               float* __restrict__ s_dst) {
  __shared__ float xl[32][128];
  __shared__ float Wl[32][128];
  int t = threadIdx.x;
  int n0 = blockIdx.x * 32;
  for (int u = t; u < 1024; u += 256) {
    int row = u >> 5, col4 = (u & 31) << 2;
    *(float4*)&xl[row][col4] = *(const float4*)(x + (size_t)(n0 + row) * 128 + col4);
  }
  int tn = t & 31, c0 = tn << 2;   // 4 cols per thread (within one head: 4|32)
  int tr = t >> 5, r0 = tr << 2;   // 4 rows per thread
  float acc[4][4];
  #pragma unroll
  for (int r = 0; r < 4; ++r)
    #pragma unroll
    for (int cc = 0; cc < 4; ++cc) acc[r][cc] = 0.f;
  for (int ic = 0; ic < 4; ++ic) {
    __syncthreads();
    for (int u = t; u < 1024; u += 256) {
      int ii = u >> 5, c4 = (u & 31) << 2;
      int hh = c4 >> 5, d0 = c4 & 31;
      *(float4*)&Wl[ii][c4] = *(const float4*)(W + hh * 4096 + (ic * 32 + ii) * 32 + d0);
    }
    __syncthreads();
    #pragma unroll 8
    for (int ii = 0; ii < 32; ++ii) {
      float4 wv = *(float4*)&Wl[ii][c0];
      int i = (ic << 5) + ii;
      #pragma unroll
      for (int r = 0; r < 4; ++r) {
        float xv = xl[r0 + r][i];
        acc[r][0] += xv * wv.x; acc[r][1] += xv * wv.y;
        acc[r][2] += xv * wv.z; acc[r][3] += xv * wv.w;
      }
    }
  }
  int hh = c0 >> 5, d0 = c0 & 31;
  float ad[4], as_[4];
  #pragma unroll
  for (int cc = 0; cc < 4; ++cc) {
    ad[cc]  = a[hh * 64 + d0 + cc];        // a_dst = a[h][0:32]
    as_[cc] = a[hh * 64 + 32 + d0 + cc];   // a_src = a[h][32:64]
  }
  #pragma unroll
  for (int r = 0; r < 4; ++r) {
    int n = n0 + r0 + r;
    float pd = 0.f, ps = 0.f;
    #pragma unroll
    for (int cc = 0; cc < 4; ++cc) {
      float v = acc[r][cc];
      hfT[(size_t)(c0 + cc) * N_NODES + n] = f2bf(v);
      pd += v * ad[cc];
      ps += v * as_[cc];
    }
    atomicAdd(&s_dst[hh * N_NODES + n], pd);
    atomicAdd(&s_src[hh * N_NODES + n], ps);
  }
}

// K1c: per-head max of s_dst
__global__ __launch_bounds__(256) void k1c_max(const float* __restrict__ s_dst,
                                               float* __restrict__ M) {
  __shared__ float red[256];
  int h = blockIdx.x, t = threadIdx.x;
  float m = -1e30f;
  for (int n = t; n < N_NODES; n += 256) m = fmaxf(m, s_dst[h * N_NODES + n]);
  red[t] = m;
  __syncthreads();
  for (int s = 128; s > 0; s >>= 1) {
    if (t < s) red[t] = fmaxf(red[t], red[t + s]);
    __syncthreads();
  }
  if (t == 0) M[h] = red[0];
}

// K2: fused masked-softmax attention aggregate. Block = 4 waves = 4 heads,
// one 16-row m-tile, k-slice of 3072. Weights built per-lane directly in
// MFMA A-operand layout (A[m=lane&15][k=quad*8+j]).
__global__ __launch_bounds__(256) void k2_attn(const int* __restrict__ adj,
                                               const unsigned short* __restrict__ hfT,
                                               const float* __restrict__ s_src,
                                               const float* __restrict__ s_dst,
                                               const float* __restrict__ M,
                                               float* __restrict__ Zpart,
                                               float* __restrict__ part) {
  __shared__ int lds_adj[16][132];  // +4 pad: m vs m+8 only 2-way (free)
  int t = threadIdx.x;
  int h = t >> 6, lane = t & 63;
  int m = lane & 15, quad = lane >> 4, kb = quad << 3;
  int bx = blockIdx.x;
  int slice = bx & 1, mt = bx >> 1;
  int i0 = mt << 4;
  int kbase = slice * 3072;
  float ssrc = s_src[h * N_NODES + i0 + m];
  float Mh = M[h];
  float e0 = ssrc + Mh;
  float ml = fmaxf(e0, 0.2f * e0);  // upper-bounding stabilizer (lrelu monotone)
  f32x4 acc0 = {0.f, 0.f, 0.f, 0.f}, acc1 = {0.f, 0.f, 0.f, 0.f};
  float zacc = 0.f;
  int nB = lane & 15;
  const unsigned short* hp0 = hfT + (size_t)(h * 32 + nB) * N_NODES;
  const unsigned short* hp1 = hfT + (size_t)(h * 32 + 16 + nB) * N_NODES;
  const float* sdp = s_dst + h * N_NODES;

  for (int it = 0; it < 24; ++it) {
    int kc = kbase + (it << 7);
    __syncthreads();
    for (int u = t; u < 512; u += 256) {
      int row = u >> 5, col4 = (u & 31) << 2;
      *(int4*)&lds_adj[row][col4] =
          *(const int4*)(adj + (size_t)(i0 + row) * N_NODES + kc + col4);
    }
    __syncthreads();
    #pragma unroll
    for (int s = 0; s < 4; ++s) {
      int kl = (s << 5) + kb;
      int kg = kc + kl;
      int4 a0 = *(const int4*)&lds_adj[m][kl];
      int4 a1 = *(const int4*)&lds_adj[m][kl + 4];
      float4 d0 = *(const float4*)(sdp + kg);
      float4 d1 = *(const float4*)(sdp + kg + 4);
      float dv[8] = {d0.x, d0.y, d0.z, d0.w, d1.x, d1.y, d1.z, d1.w};
      int av[8] = {a0.x, a0.y, a0.z, a0.w, a1.x, a1.y, a1.z, a1.w};
      float w[8];
      #pragma unroll
      for (int j = 0; j < 8; ++j) {
        float e = ssrc + dv[j];
        float lr = fmaxf(e, 0.2f * e);
        float ex = __expf(lr - ml);
        w[j] = (av[j] > 0) ? ex : 0.f;
        zacc += w[j];
      }
      union { short8 v; unsigned short u[8]; } afr;
      #pragma unroll
      for (int j = 0; j < 8; ++j) afr.u[j] = f2bf(w[j]);
      union { int4 i; short8 v; } b0, b1;
      b0.i = *(const int4*)(hp0 + kg);
      b1.i = *(const int4*)(hp1 + kg);
      acc0 = __builtin_amdgcn_mfma_f32_16x16x32_bf16(afr.v, b0.v, acc0, 0, 0, 0);
      acc1 = __builtin_amdgcn_mfma_f32_16x16x32_bf16(afr.v, b1.v, acc1, 0, 0, 0);
    }
  }
  // Z: sum lane partials across the 4 quads (same m)
  zacc += __shfl_xor(zacc, 16);
  zacc += __shfl_xor(zacc, 32);
  if (lane < 16) Zpart[(slice * 4 + h) * N_NODES + i0 + lane] = zacc;
  // store unnormalized partials directly in final (h, i, d) layout
  float* pb = part + (size_t)slice * (N_NODES * CDIM) + h * (N_NODES * HDIM) +
              (size_t)i0 * HDIM;
  #pragma unroll
  for (int r = 0; r < 4; ++r) {
    int row = (quad << 2) + r;  // D layout: col=lane&15, row=quad*4+reg
    pb[row * 32 + nB] = acc0[r];
    pb[row * 32 + 16 + nB] = acc1[r];
  }
}

// K3: out = (part0 + part1) / (Z0 + Z1), already in final flat layout.
__global__ __launch_bounds__(256) void k3_final(const float* __restrict__ part,
                                                const float* __restrict__ Zpart,
                                                float* __restrict__ out) {
  unsigned int idx = blockIdx.x * 256 + threadIdx.x;
  unsigned int h = idx / 196608u;           // N_NODES*HDIM
  unsigned int rem = idx - h * 196608u;
  unsigned int i = rem >> 5;
  float z = Zpart[h * N_NODES + i] + Zpart[4 * N_NODES + h * N_NODES + i];
  out[idx] = (part[idx] + part[786432u + idx]) / z;
}

extern "C" void kernel_launch(void* const* d_in, const int* in_sizes, int n_in,
                              void* d_out, int out_size, void* d_ws, size_t ws_size,
                              hipStream_t stream) {
  const float* x = (const float*)d_in[0];
  const int* adj = (const int*)d_in[1];
  const float* W = (const float*)d_in[2];
  const float* a = (const float*)d_in[3];
  float* out = (float*)d_out;

  float* wsf = (float*)d_ws;
  unsigned short* hfT = (unsigned short*)wsf;   // 128*6144 bf16 = 393216 floats
  float* s_src = wsf + 393216;                  // 4*6144
  float* s_dst = s_src + 24576;                 // 4*6144
  float* M     = s_dst + 24576;                 // 4 (+pad)
  float* Zpart = M + 64;                        // 2*4*6144 = 49152
  float* part  = Zpart + 49152;                 // 2*786432
  // total ~8.26 MB of d_ws

  hipMemsetAsync(s_src, 0, 2 * 24576 * sizeof(float), stream);
  hipLaunchKernelGGL(k1_feat, dim3(192), dim3(256), 0, stream, x, W, a, hfT, s_src, s_dst);
  hipLaunchKernelGGL(k1c_max, dim3(4), dim3(256), 0, stream, s_dst, M);
  hipLaunchKernelGGL(k2_attn, dim3(768), dim3(256), 0, stream, adj, hfT, s_src, s_dst, M,
                     Zpart, part);
  hipLaunchKernelGGL(k3_final, dim3(3072), dim3(256), 0, stream, part, Zpart, out);
}

// Round 2
// 336.498 us; speedup vs baseline: 1.0598x; 1.0598x over previous
//
#include <hip/hip_runtime.h>
#include <stdint.h>

#define N_NODES 6144
#define LOG2E 1.44269504088896f

typedef float f32x4 __attribute__((ext_vector_type(4)));
typedef short short8 __attribute__((ext_vector_type(8)));

extern "C" __device__ float __ocml_native_exp2_f32(float);

__device__ __forceinline__ unsigned short f2bf(float f) {
  union { float f; unsigned int u; } v; v.f = f;
  unsigned int u = v.u;
  u += 0x7FFFu + ((u >> 16) & 1u);
  return (unsigned short)(u >> 16);
}

// pack two floats -> two bf16 (round-half-up) in one u32: hi=b, lo=a
__device__ __forceinline__ unsigned int pack2bf(float a, float b) {
  unsigned int ua = __float_as_uint(a) + 0x8000u;
  unsigned int ub = __float_as_uint(b) + 0x8000u;
  return __builtin_amdgcn_perm(ub, ua, 0x07060302u);  // {ub[3],ub[2],ua[3],ua[2]}
}

// K1: h = x*W (fp32). Writes hfT (bf16, [c][n] transposed) and
// s_src2/s_dst2 = (h . a_{src,dst}) * log2(e)  (pre-scaled for exp2 in K2).
__global__ __launch_bounds__(256) void k1_feat(const float* __restrict__ x,
                                               const float* __restrict__ W,
                                               const float* __restrict__ a,
                                               unsigned short* __restrict__ hfT,
                                               float* __restrict__ s_src2,
                                               float* __restrict__ s_dst2) {
  __shared__ float xl[16][128];
  __shared__ float Wl[32][128];
  int t = threadIdx.x;
  int n0 = blockIdx.x * 16;
  for (int u = t; u < 512; u += 256) {
    int row = u >> 5, c4 = (u & 31) << 2;
    *(float4*)&xl[row][c4] = *(const float4*)(x + (size_t)(n0 + row) * 128 + c4);
  }
  int tn = t & 31, c0 = tn << 2;   // 4 channel-cols per thread
  int tr = t >> 5, r0 = tr << 1;   // 2 rows per thread
  float acc[2][4];
  #pragma unroll
  for (int r = 0; r < 2; ++r)
    #pragma unroll
    for (int cc = 0; cc < 4; ++cc) acc[r][cc] = 0.f;
  for (int ic = 0; ic < 4; ++ic) {
    __syncthreads();
    for (int u = t; u < 1024; u += 256) {
      int ii = u >> 5, c4 = (u & 31) << 2;
      int hh = c4 >> 5, d0 = c4 & 31;
      *(float4*)&Wl[ii][c4] = *(const float4*)(W + hh * 4096 + (ic * 32 + ii) * 32 + d0);
    }
    __syncthreads();
    #pragma unroll 8
    for (int ii = 0; ii < 32; ++ii) {
      float4 wv = *(float4*)&Wl[ii][c0];
      int i = (ic << 5) + ii;
      float x0 = xl[r0][i], x1 = xl[r0 + 1][i];
      acc[0][0] += x0 * wv.x; acc[0][1] += x0 * wv.y;
      acc[0][2] += x0 * wv.z; acc[0][3] += x0 * wv.w;
      acc[1][0] += x1 * wv.x; acc[1][1] += x1 * wv.y;
      acc[1][2] += x1 * wv.z; acc[1][3] += x1 * wv.w;
    }
  }
  int hh = c0 >> 5, d0 = c0 & 31;
  float4 adv = *(const float4*)(a + hh * 64 + d0);        // a_dst = a[h][0:32]
  float4 asv = *(const float4*)(a + hh * 64 + 32 + d0);   // a_src = a[h][32:64]
  #pragma unroll
  for (int r = 0; r < 2; ++r) {
    int n = n0 + r0 + r;
    #pragma unroll
    for (int cc = 0; cc < 4; ++cc)
      hfT[(size_t)(c0 + cc) * N_NODES + n] = f2bf(acc[r][cc]);
    float pd = acc[r][0] * adv.x + acc[r][1] * adv.y + acc[r][2] * adv.z + acc[r][3] * adv.w;
    float ps = acc[r][0] * asv.x + acc[r][1] * asv.y + acc[r][2] * asv.z + acc[r][3] * asv.w;
    pd += __shfl_xor(pd, 1); ps += __shfl_xor(ps, 1);
    pd += __shfl_xor(pd, 2); ps += __shfl_xor(ps, 2);
    pd += __shfl_xor(pd, 4); ps += __shfl_xor(ps, 4);
    if ((tn & 7) == 0) {
      s_dst2[hh * N_NODES + n] = pd * LOG2E;
      s_src2[hh * N_NODES + n] = ps * LOG2E;
    }
  }
}

// K2: fused masked-softmax attention aggregate. No LDS, no barriers.
// Block = 4 waves = 4 heads on one 16-row m-tile, k-slice of 1536 (split 4).
// Weights built per-lane directly in MFMA A-layout (A[m=lane&15][k=quad*8+j]).
// Z row-sums come from a third MFMA against a ones-B fragment.
__global__ __launch_bounds__(256) void k2_attn(const int* __restrict__ adj,
                                               const unsigned short* __restrict__ hfT,
                                               const float* __restrict__ s_src2,
                                               const float* __restrict__ s_dst2,
                                               float* __restrict__ Zpart,
                                               float* __restrict__ part) {
  int t = threadIdx.x;
  int h = t >> 6, lane = t & 63;
  int m = lane & 15, quad = lane >> 4;
  int bx = blockIdx.x;
  int slice = bx & 3, mt = bx >> 2;
  int i0 = mt << 4;
  int kbase = slice * 1536;
  float ssrc2 = s_src2[h * N_NODES + i0 + m];
  f32x4 acc0 = {0.f, 0.f, 0.f, 0.f}, acc1 = {0.f, 0.f, 0.f, 0.f};
  f32x4 accz = {0.f, 0.f, 0.f, 0.f};
  int nB = m;
  const int* arow = adj + (size_t)(i0 + m) * N_NODES + kbase + (quad << 3);
  const float* dp = s_dst2 + h * N_NODES + kbase + (quad << 3);
  const unsigned short* hp0 = hfT + (size_t)(h * 32 + nB) * N_NODES + kbase + (quad << 3);
  const unsigned short* hp1 = hp0 + (size_t)16 * N_NODES;
  union { unsigned int u[4]; short8 v; } ones;
  #pragma unroll
  for (int q = 0; q < 4; ++q) ones.u[q] = 0x3F803F80u;  // bf16 1.0 pairs

  #pragma unroll 4
  for (int it = 0; it < 48; ++it) {
    int kk = it << 5;
    int4 a0 = *(const int4*)(arow + kk);
    int4 a1 = *(const int4*)(arow + kk + 4);
    float4 d0 = *(const float4*)(dp + kk);
    float4 d1 = *(const float4*)(dp + kk + 4);
    union { int4 i; short8 v; } b0, b1;
    b0.i = *(const int4*)(hp0 + kk);
    b1.i = *(const int4*)(hp1 + kk);
    float dv[8] = {d0.x, d0.y, d0.z, d0.w, d1.x, d1.y, d1.z, d1.w};
    int av[8] = {a0.x, a0.y, a0.z, a0.w, a1.x, a1.y, a1.z, a1.w};
    float w[8];
    #pragma unroll
    for (int j = 0; j < 8; ++j) {
      float e = ssrc2 + dv[j];                       // already * log2e
      float lr = fmaxf(e, 0.2f * e);                 // leaky-relu (log2 domain)
      float ex = __ocml_native_exp2_f32(lr);         // v_exp_f32
      w[j] = (av[j] > 0) ? ex : 0.f;
    }
    union { unsigned int u[4]; short8 v; } afr;
    #pragma unroll
    for (int j = 0; j < 4; ++j) afr.u[j] = pack2bf(w[2 * j], w[2 * j + 1]);
    acc0 = __builtin_amdgcn_mfma_f32_16x16x32_bf16(afr.v, b0.v, acc0, 0, 0, 0);
    acc1 = __builtin_amdgcn_mfma_f32_16x16x32_bf16(afr.v, b1.v, acc1, 0, 0, 0);
    accz = __builtin_amdgcn_mfma_f32_16x16x32_bf16(afr.v, ones.v, accz, 0, 0, 0);
  }
  // accz col 0 lanes hold row-sums: lane(quad, nB==0) has rows quad*4+r
  if (nB == 0) {
    #pragma unroll
    for (int r = 0; r < 4; ++r)
      Zpart[(size_t)(slice * 4 + h) * N_NODES + i0 + (quad << 2) + r] = accz[r];
  }
  // unnormalized partials directly in final (h, i, d) flat layout
  float* pb = part + (size_t)slice * (N_NODES * 128) + h * (N_NODES * 32) +
              (size_t)i0 * 32;
  #pragma unroll
  for (int r = 0; r < 4; ++r) {
    int row = (quad << 2) + r;  // D layout: col=lane&15, row=quad*4+reg
    pb[row * 32 + nB] = acc0[r];
    pb[row * 32 + 16 + nB] = acc1[r];
  }
}

// K3: out = sum_s part[s] / sum_s Z[s], vectorized float4.
__global__ __launch_bounds__(256) void k3_final(const float* __restrict__ part,
                                                const float* __restrict__ Zpart,
                                                float* __restrict__ out) {
  unsigned int idx4 = blockIdx.x * 256 + threadIdx.x;   // float4 index
  unsigned int h = idx4 / 49152u;                       // 6144*32/4
  unsigned int i = (idx4 - h * 49152u) >> 3;            // 8 float4 per node-row
  float z = 0.f;
  #pragma unroll
  for (int s = 0; s < 4; ++s) z += Zpart[(s * 4 + h) * N_NODES + i];
  f32x4 p = {0.f, 0.f, 0.f, 0.f};
  const f32x4* P = (const f32x4*)part;
  #pragma unroll
  for (int s = 0; s < 4; ++s) p += P[(size_t)s * 196608u + idx4];
  float rz = 1.0f / z;
  f32x4* O = (f32x4*)out;
  O[idx4] = p * rz;
}

extern "C" void kernel_launch(void* const* d_in, const int* in_sizes, int n_in,
                              void* d_out, int out_size, void* d_ws, size_t ws_size,
                              hipStream_t stream) {
  const float* x = (const float*)d_in[0];
  const int* adj = (const int*)d_in[1];
  const float* W = (const float*)d_in[2];
  const float* a = (const float*)d_in[3];
  float* out = (float*)d_out;

  float* wsf = (float*)d_ws;
  unsigned short* hfT = (unsigned short*)wsf;   // 128*6144 bf16 = 393216 floats
  float* s_src2 = wsf + 393216;                 // 4*6144
  float* s_dst2 = s_src2 + 24576;               // 4*6144
  float* Zpart  = s_dst2 + 24576;               // 4 slices * 4*6144 = 98304
  float* part   = Zpart + 98304;                // 4 slices * 786432
  // total ~14.8 MB of d_ws

  hipLaunchKernelGGL(k1_feat, dim3(384), dim3(256), 0, stream, x, W, a, hfT, s_src2, s_dst2);
  hipLaunchKernelGGL(k2_attn, dim3(1536), dim3(256), 0, stream, adj, hfT, s_src2, s_dst2,
                     Zpart, part);
  hipLaunchKernelGGL(k3_final, dim3(768), dim3(256), 0, stream, part, Zpart, out);
}